// Round 2
// baseline (325.564 us; speedup 1.0000x reference)
//
#include <hip/hip_runtime.h>

#define NB 32
#define NI 2048
#define NP 16
#define NJ 32
#define ND 32
#define EPSF 1e-7f

typedef __attribute__((ext_vector_type(8))) short bf16x8;
typedef __attribute__((ext_vector_type(16))) float f32x16;
typedef __attribute__((ext_vector_type(4))) float f32x4;

static __device__ __forceinline__ unsigned cvt_pk_bf16(float lo, float hi) {
  unsigned r;
  asm("v_cvt_pk_bf16_f32 %0, %1, %2" : "=v"(r) : "v"(lo), "v"(hi));
  return r;
}

static __device__ __forceinline__ f32x16 mfma_bf16(bf16x8 a, bf16x8 b, f32x16 c) {
  return __builtin_amdgcn_mfma_f32_32x32x16_bf16(a, b, c, 0, 0, 0);
}

// A operand for U^T = W^T(d x p) @ X^T(p x b), one (i,j).
// lane l: m = d = l&31, k = p = 8*(l>>5) + e  (e = 0..7)
static __device__ __forceinline__ bf16x8 load_wfrag(const float* __restrict__ W,
                                                    int i, int j, int h, int d) {
  const float* wp = W + (((size_t)i * NJ + j) * NP + h * 8) * ND + d;
  union { unsigned u[4]; bf16x8 v; } wf;
  wf.u[0] = cvt_pk_bf16(wp[0 * ND], wp[1 * ND]);
  wf.u[1] = cvt_pk_bf16(wp[2 * ND], wp[3 * ND]);
  wf.u[2] = cvt_pk_bf16(wp[4 * ND], wp[5 * ND]);
  wf.u[3] = cvt_pk_bf16(wp[6 * ND], wp[7 * ND]);
  return wf.v;
}

// B operand: lane l: k = p = 8*(l>>5)+e, n = b = l&31
static __device__ __forceinline__ bf16x8 load_xfrag(const unsigned short* __restrict__ Xt,
                                                    int i, int b, int h) {
  return *(const bf16x8*)(Xt + ((size_t)i * NB + b) * NP + h * 8);
}

// ---------- prep: inputs[b][i][p] (f32) -> Xt[i][b][p] (bf16) ----------
__global__ __launch_bounds__(256) void kern_prep(const float* __restrict__ in,
                                                 unsigned short* __restrict__ Xt) {
  const int t = blockIdx.x * 256 + threadIdx.x;   // 262144 threads, 4 elems each
  const int rest = t >> 2;                        // b*NI + i
  const int p4 = (t & 3) * 4;
  const int i = rest & (NI - 1);
  const int b = rest >> 11;
  f32x4 x = *(const f32x4*)(in + (size_t)rest * NP + p4);
  uint2 v;
  v.x = cvt_pk_bf16(x[0], x[1]);
  v.y = cvt_pk_bf16(x[2], x[3]);
  *(uint2*)(Xt + ((size_t)i * NB + b) * NP + p4) = v;
}

// ---------- fused: [logits -> softmax ->] weighted partial sum over i-chunk ----
// 512 threads = 8 waves; wave w owns j = w*4 + t (t=0..3).
// block ch handles i in [ch*ipb, ch*ipb+ipb). part[j][ch][b][d] partials.
// UNIFORM: c = 1/32 (routing iter 0), no logits/softmax needed.
template <bool UNIFORM>
__global__ __launch_bounds__(512) void kern_fused(const float* __restrict__ W,
                                                  const unsigned short* __restrict__ Xt,
                                                  const float* __restrict__ vsum,
                                                  float* __restrict__ part,
                                                  int ipb, int nch) {
  const int tid = threadIdx.x;
  const int w = tid >> 6;
  const int lane = tid & 63;
  const int b = lane & 31;
  const int h = lane >> 5;
  const int ch = blockIdx.x;

  // register-resident vsum fragment: vs[t][q][e] = vsum[b][j=w*4+t][8q + 4h + e]
  f32x4 vs[4][4];
  if (!UNIFORM) {
#pragma unroll
    for (int t = 0; t < 4; ++t) {
      const int j = w * 4 + t;
#pragma unroll
      for (int q = 0; q < 4; ++q)
        vs[t][q] = *(const f32x4*)(vsum + ((size_t)b * NJ + j) * ND + q * 8 + h * 4);
    }
  }

  f32x16 sacc[4] = {};
  __shared__ float lgt[NJ][33];

  for (int ii = 0; ii < ipb; ++ii) {
    const int i = ch * ipb + ii;
    const bf16x8 xf = load_xfrag(Xt, i, b, h);
    if (UNIFORM) {
#pragma unroll
      for (int t = 0; t < 4; ++t)
        sacc[t] = mfma_bf16(load_wfrag(W, i, w * 4 + t, h, b), xf, sacc[t]);
    } else {
      f32x16 um[4];
      float lg[4];
#pragma unroll
      for (int t = 0; t < 4; ++t) {
        const int j = w * 4 + t;
        f32x16 z = {};
        um[t] = mfma_bf16(load_wfrag(W, i, j, h, b), xf, z);  // um[r]=U^T[d(r)][b]
        float p = 0.f;
#pragma unroll
        for (int r = 0; r < 16; ++r)
          p += um[t][r] * vs[t][r >> 2][r & 3];   // d(r) = (r&3) + 8*(r>>2) + 4h
        p += __shfl_xor(p, 32);                   // add partner half's 16 d's
        lg[t] = p;
      }
      if (h == 0) {
#pragma unroll
        for (int t = 0; t < 4; ++t) lgt[w * 4 + t][b] = lg[t];
      }
      __syncthreads();
      // per-(b,i) softmax over j (each thread reduces its own b's column)
      float mx = -3.0e38f;
#pragma unroll
      for (int jj = 0; jj < NJ; ++jj) mx = fmaxf(mx, lgt[jj][b]);
      float den = 0.f;
#pragma unroll
      for (int jj = 0; jj < NJ; ++jj) den += expf(lgt[jj][b] - mx);
      const float inv = 1.0f / den;
#pragma unroll
      for (int t = 0; t < 4; ++t) {
        const float c = expf(lg[t] - mx) * inv;
#pragma unroll
        for (int r = 0; r < 16; ++r) sacc[t][r] += c * um[t][r];
      }
      __syncthreads();   // protect lgt before next i overwrites it
    }
  }

#pragma unroll
  for (int t = 0; t < 4; ++t) {
    const int j = w * 4 + t;
#pragma unroll
    for (int r = 0; r < 16; ++r) {
      const float val = UNIFORM ? sacc[t][r] * (1.0f / 32.0f) : sacc[t][r];
      const int d = (r & 3) + 8 * (r >> 2) + 4 * h;
      part[(((size_t)j * nch + ch) * NB + b) * ND + d] = val;
    }
  }
}

// ---------- reduce partials + squash + vsum/out ----------
// grid: 32 blocks (one j), 1024 threads: t = b*32 + d.
__global__ __launch_bounds__(1024) void kern_squash(const float* __restrict__ part,
                                                    float* __restrict__ vsum,
                                                    float* __restrict__ out,
                                                    int mode, int nch) {
  const int j = blockIdx.x;
  const int t = threadIdx.x;
  const int b = t >> 5;
  const int d = t & 31;
  float s = 0.f;
  for (int ch = 0; ch < nch; ++ch)
    s += part[(((size_t)j * nch + ch) * NB + b) * ND + d];

  __shared__ float sl[32][33];
  __shared__ float fb[32];
  sl[b][d] = s;
  __syncthreads();
  if (t < 32) {
    float n2 = 0.f;
#pragma unroll
    for (int dd = 0; dd < ND; ++dd) { const float x = sl[t][dd]; n2 += x * x; }
    fb[t] = n2 / ((1.0f + n2) * sqrtf(n2 + EPSF));
  }
  __syncthreads();
  const float v = s * fb[b];
  const int idx = (b * NJ + j) * ND + d;
  if (mode == 0)      vsum[idx] = v;        // iter0: vsum := v0 (never read-before-write)
  else if (mode == 1) vsum[idx] += v;       // iter1: vsum := v0+v1
  else                out[idx] = v;         // iter2: final output [B,J,D]
}

extern "C" void kernel_launch(void* const* d_in, const int* in_sizes, int n_in,
                              void* d_out, int out_size, void* d_ws, size_t ws_size,
                              hipStream_t stream) {
  const float* inp = (const float*)d_in[0];
  const float* W   = (const float*)d_in[1];
  // defensive: inputs is 1M elems, W is 33.5M elems
  if (n_in >= 2 && in_sizes[0] > in_sizes[1]) { const float* tmp = inp; inp = W; W = tmp; }
  float* out = (float*)d_out;
  char* ws = (char*)d_ws;
  (void)out_size;

  // adaptive chunk count so workspace fits: need 2MB(Xt) + nch*128KB(part) + 128KB(vsum)
  int nch = 256;
  while (nch > 32 &&
         (size_t)(2u << 20) + (size_t)nch * 131072u + 131072u > ws_size)
    nch >>= 1;
  const int ipb = NI / nch;

  unsigned short* Xt = (unsigned short*)ws;                          // 2 MB
  float* part = (float*)(ws + (2u << 20));                           // nch*128 KB
  float* vsum = (float*)(ws + (2u << 20) + (size_t)nch * 131072u);   // 128 KB

  kern_prep<<<1024, 256, 0, stream>>>(inp, Xt);

  // iter 0: uniform c = 1/32
  kern_fused<true><<<nch, 512, 0, stream>>>(W, Xt, nullptr, part, ipb, nch);
  kern_squash<<<32, 1024, 0, stream>>>(part, vsum, out, 0, nch);

  // iter 1
  kern_fused<false><<<nch, 512, 0, stream>>>(W, Xt, vsum, part, ipb, nch);
  kern_squash<<<32, 1024, 0, stream>>>(part, vsum, out, 1, nch);

  // iter 2
  kern_fused<false><<<nch, 512, 0, stream>>>(W, Xt, vsum, part, ipb, nch);
  kern_squash<<<32, 1024, 0, stream>>>(part, vsum, out, 2, nch);
}

// Round 5
// 157.295 us; speedup vs baseline: 2.0698x; 2.0698x over previous
//
#include <hip/hip_runtime.h>

#define NB 32
#define NI 2048
#define NP 16
#define NJ 32
#define ND 32
#define EPSF 1e-7f

typedef __attribute__((ext_vector_type(8))) short bf16x8;
typedef __attribute__((ext_vector_type(16))) float f32x16;
typedef __attribute__((ext_vector_type(4))) float f32x4;

static __device__ __forceinline__ unsigned cvt_pk_bf16(float lo, float hi) {
  unsigned r;
  asm("v_cvt_pk_bf16_f32 %0, %1, %2" : "=v"(r) : "v"(lo), "v"(hi));
  return r;
}

static __device__ __forceinline__ f32x16 mfma_bf16(bf16x8 a, bf16x8 b, f32x16 c) {
  return __builtin_amdgcn_mfma_f32_32x32x16_bf16(a, b, c, 0, 0, 0);
}

// A operand for U^T = W^T(d x p) @ X^T(p x b), one (i,j), from raw f32 W.
// lane l: m = d = l&31, k = p = 8*(l>>5) + e  (e = 0..7)
static __device__ __forceinline__ bf16x8 load_wfrag_f32(const float* __restrict__ W,
                                                        int i, int j, int h, int d) {
  const float* wp = W + (((size_t)i * NJ + j) * NP + h * 8) * ND + d;
  union { unsigned u[4]; bf16x8 v; } wf;
  wf.u[0] = cvt_pk_bf16(wp[0 * ND], wp[1 * ND]);
  wf.u[1] = cvt_pk_bf16(wp[2 * ND], wp[3 * ND]);
  wf.u[2] = cvt_pk_bf16(wp[4 * ND], wp[5 * ND]);
  wf.u[3] = cvt_pk_bf16(wp[6 * ND], wp[7 * ND]);
  return wf.v;
}

// B operand: lane l: k = p = 8*(l>>5)+e, n = b = l&31
static __device__ __forceinline__ bf16x8 load_xfrag(const unsigned short* __restrict__ Xt,
                                                    int i, int b, int h) {
  return *(const bf16x8*)(Xt + ((size_t)i * NB + b) * NP + h * 8);
}

// ---------- prep: inputs[b][i][p] (f32) -> Xt[i][b][p] (bf16) ----------
__global__ __launch_bounds__(256) void kern_prep(const float* __restrict__ in,
                                                 unsigned short* __restrict__ Xt) {
  const int t = blockIdx.x * 256 + threadIdx.x;   // 262144 threads, 4 elems each
  const int rest = t >> 2;                        // b*NI + i
  const int p4 = (t & 3) * 4;
  const int i = rest & (NI - 1);
  const int b = rest >> 11;
  f32x4 x = *(const f32x4*)(in + (size_t)rest * NP + p4);
  uint2 v;
  v.x = cvt_pk_bf16(x[0], x[1]);
  v.y = cvt_pk_bf16(x[2], x[3]);
  *(uint2*)(Xt + ((size_t)i * NB + b) * NP + p4) = v;
}

// ---------- fused: [logits -> softmax ->] weighted partial sum over i-chunk ----
// 512 threads = 8 waves; wave w owns j = w*4 + t (t=0..3).
// block ch handles i in [ch*ipb, ch*ipb+ipb). part[j][ch][b][d] partials.
// UNIFORM: c = 1/32 (routing iter 0), no logits/softmax needed.
template <bool UNIFORM>
__global__ __launch_bounds__(512) void kern_fused(const float* __restrict__ W,
                                                  const unsigned short* __restrict__ Xt,
                                                  const float* __restrict__ vsum,
                                                  float* __restrict__ part,
                                                  int ipb, int nch) {
  const int tid = threadIdx.x;
  const int w = tid >> 6;
  const int lane = tid & 63;
  const int b = lane & 31;
  const int h = lane >> 5;
  const int ch = blockIdx.x;

  // register-resident vsum fragment: vs[t][q][e] = vsum[b][j=w*4+t][8q + 4h + e]
  f32x4 vs[4][4];
  if (!UNIFORM) {
#pragma unroll
    for (int t = 0; t < 4; ++t) {
      const int j = w * 4 + t;
#pragma unroll
      for (int q = 0; q < 4; ++q)
        vs[t][q] = *(const f32x4*)(vsum + ((size_t)b * NJ + j) * ND + q * 8 + h * 4);
    }
  }

  f32x16 sacc[4] = {};
  __shared__ float lgt[NJ][33];

  for (int ii = 0; ii < ipb; ++ii) {
    const int i = ch * ipb + ii;
    const bf16x8 xf = load_xfrag(Xt, i, b, h);
    if (UNIFORM) {
#pragma unroll
      for (int t = 0; t < 4; ++t)
        sacc[t] = mfma_bf16(load_wfrag_f32(W, i, w * 4 + t, h, b), xf, sacc[t]);
    } else {
      f32x16 um[4];
      float lg[4];
#pragma unroll
      for (int t = 0; t < 4; ++t) {
        const int j = w * 4 + t;
        f32x16 z = {};
        um[t] = mfma_bf16(load_wfrag_f32(W, i, j, h, b), xf, z);  // um[r]=U^T[d(r)][b]
        float p = 0.f;
#pragma unroll
        for (int r = 0; r < 16; ++r)
          p += um[t][r] * vs[t][r >> 2][r & 3];   // d(r) = (r&3) + 8*(r>>2) + 4h
        p += __shfl_xor(p, 32);                   // add partner half's 16 d's
        lg[t] = p;
      }
      if (h == 0) {
#pragma unroll
        for (int t = 0; t < 4; ++t) lgt[w * 4 + t][b] = lg[t];
      }
      __syncthreads();
      // per-(b,i) softmax over j (each thread reduces its own b's column)
      float mx = -3.0e38f;
#pragma unroll
      for (int jj = 0; jj < NJ; ++jj) mx = fmaxf(mx, lgt[jj][b]);
      float den = 0.f;
#pragma unroll
      for (int jj = 0; jj < NJ; ++jj) den += expf(lgt[jj][b] - mx);
      const float inv = 1.0f / den;
#pragma unroll
      for (int t = 0; t < 4; ++t) {
        const float c = expf(lg[t] - mx) * inv;
#pragma unroll
        for (int r = 0; r < 16; ++r) sacc[t][r] += c * um[t][r];
      }
      __syncthreads();   // protect lgt before next i overwrites it
    }
  }

#pragma unroll
  for (int t = 0; t < 4; ++t) {
    const int j = w * 4 + t;
#pragma unroll
    for (int r = 0; r < 16; ++r) {
      const float val = UNIFORM ? sacc[t][r] * (1.0f / 32.0f) : sacc[t][r];
      const int d = (r & 3) + 8 * (r >> 2) + 4 * h;
      part[(((size_t)j * nch + ch) * NB + b) * ND + d] = val;
    }
  }
}

// ---------- stage-1 reduce: 32-chunk groups -> part2[j][r][b][d] ----------
// grid: 32*RG blocks, 1024 threads (t = b*32 + d). Coalesced full-GPU read of part.
__global__ __launch_bounds__(1024) void kern_reduce1(const float* __restrict__ part,
                                                     float* __restrict__ part2,
                                                     int nch, int RG) {
  const int j = blockIdx.x / RG;
  const int r = blockIdx.x % RG;
  const int t = threadIdx.x;
  const int b = t >> 5;
  const int d = t & 31;
  float s = 0.f;
#pragma unroll 4
  for (int c = 0; c < 32; ++c)
    s += part[(((size_t)j * nch + r * 32 + c) * NB + b) * ND + d];
  part2[(((size_t)j * RG + r) * NB + b) * ND + d] = s;
}

// ---------- final reduce + squash + vsum/out ----------
// grid: 32 blocks (one j), 1024 threads: t = b*32 + d.
__global__ __launch_bounds__(1024) void kern_squash(const float* __restrict__ part2,
                                                    float* __restrict__ vsum,
                                                    float* __restrict__ out,
                                                    int mode, int RG) {
  const int j = blockIdx.x;
  const int t = threadIdx.x;
  const int b = t >> 5;
  const int d = t & 31;
  float s = 0.f;
  for (int r = 0; r < RG; ++r)
    s += part2[(((size_t)j * RG + r) * NB + b) * ND + d];

  __shared__ float sl[32][33];
  __shared__ float fb[32];
  sl[b][d] = s;
  __syncthreads();
  if (t < 32) {
    float n2 = 0.f;
#pragma unroll
    for (int dd = 0; dd < ND; ++dd) { const float x = sl[t][dd]; n2 += x * x; }
    fb[t] = n2 / ((1.0f + n2) * sqrtf(n2 + EPSF));
  }
  __syncthreads();
  const float v = s * fb[b];
  const int idx = (b * NJ + j) * ND + d;
  if (mode == 0)      vsum[idx] = v;        // iter0: vsum := v0 (never read-before-write)
  else if (mode == 1) vsum[idx] += v;       // iter1: vsum := v0+v1
  else                out[idx] = v;         // iter2: final output [B,J,D]
}

extern "C" void kernel_launch(void* const* d_in, const int* in_sizes, int n_in,
                              void* d_out, int out_size, void* d_ws, size_t ws_size,
                              hipStream_t stream) {
  const float* inp = (const float*)d_in[0];
  const float* W   = (const float*)d_in[1];
  // defensive: inputs is 1M elems, W is 33.5M elems
  if (n_in >= 2 && in_sizes[0] > in_sizes[1]) { const float* tmp = inp; inp = W; W = tmp; }
  float* out = (float*)d_out;
  char* ws = (char*)d_ws;
  (void)out_size;

  // layout identical to the PASSING R2 kernel: Xt@0 (2MB) | part@2MB (nch*128KB)
  // | vsum right after part (128KB) | part2 appended after vsum (RG*128KB).
  int nch = 256;
  while (nch > 32 &&
         (size_t)(2u << 20) + (size_t)nch * 131072u + 131072u +
             (size_t)(nch / 32) * 131072u > ws_size)
    nch >>= 1;
  const int ipb = NI / nch;
  const int RG = nch / 32;

  unsigned short* Xt = (unsigned short*)ws;
  float* part  = (float*)(ws + (2u << 20));
  float* vsum  = part + (size_t)NJ * nch * NB * ND;   // full part extent (nch*32768 floats)
  float* part2 = vsum + (size_t)NB * NJ * ND;         // after vsum (32768 floats)

  kern_prep<<<1024, 256, 0, stream>>>(inp, Xt);

  // iter 0: uniform c = 1/32
  kern_fused<true><<<nch, 512, 0, stream>>>(W, Xt, nullptr, part, ipb, nch);
  kern_reduce1<<<32 * RG, 1024, 0, stream>>>(part, part2, nch, RG);
  kern_squash<<<32, 1024, 0, stream>>>(part2, vsum, out, 0, RG);

  // iter 1
  kern_fused<false><<<nch, 512, 0, stream>>>(W, Xt, vsum, part, ipb, nch);
  kern_reduce1<<<32 * RG, 1024, 0, stream>>>(part, part2, nch, RG);
  kern_squash<<<32, 1024, 0, stream>>>(part2, vsum, out, 1, RG);

  // iter 2
  kern_fused<false><<<nch, 512, 0, stream>>>(W, Xt, vsum, part, ipb, nch);
  kern_reduce1<<<32 * RG, 1024, 0, stream>>>(part, part2, nch, RG);
  kern_squash<<<32, 1024, 0, stream>>>(part2, vsum, out, 2, RG);
}